// Round 2
// baseline (350.165 us; speedup 1.0000x reference)
//
#include <hip/hip_runtime.h>
#include <math.h>

// ChannelDropout, split into two dispatches:
//   K1 (scale_kernel):  scale[row] = kept(row) / (1e-8 + proba(row))
//       one thread per row; 100 MC centers staged in LDS (800 B);
//       17472 rows -> 69 blocks; runs in a few microseconds.
//   K2 (stream_kernel): out[row, :] = sig[row, :] * scale[row]
//       one block (256 thr) per row; ONE uniform (scalar-cache) load of
//       scale, then pure float4 nontemporal stream. Structurally a
//       memcpy-with-scale -> should match the ~6.5 TB/s fill ceiling.
//
// scale[] lives in d_ws (rows*4 = 70 KB). If the workspace is too small
// we fall back to the previous fused single-kernel version.
//
// NOTE on numerics: keep sqrtf(d2) > 0.2f (NOT d2 > 0.04f) so borderline
// comparisons round identically to the JAX reference.

typedef float v4f __attribute__((ext_vector_type(4)));
typedef float v2f __attribute__((ext_vector_type(2)));

// ---------------- K1: per-row scale --------------------------------------
__global__ __launch_bounds__(256) void scale_kernel(
    const float* __restrict__ pos,
    const float* __restrict__ center,
    const float* __restrict__ mc,
    float* __restrict__ scale,
    int rows, int NMC)
{
    __shared__ float s_mc[256];            // up to 128 (x,y) centers
    const int t = threadIdx.x;
    for (int i = t; i < 2 * NMC; i += 256) s_mc[i] = mc[i];
    __syncthreads();

    const int row = blockIdx.x * 256 + t;
    if (row >= rows) return;

    const v2f p = *(const v2f*)(pos + 2 * (size_t)row);
    float cnt = 0.0f;
    for (int i = 0; i < NMC; ++i) {
        const float dx = p.x - s_mc[2 * i + 0];
        const float dy = p.y - s_mc[2 * i + 1];
        cnt += (sqrtf(dx * dx + dy * dy) > 0.2f) ? 1.0f : 0.0f;
    }
    const float ddx  = p.x - center[0];
    const float ddy  = p.y - center[1];
    const float kept = (sqrtf(ddx * ddx + ddy * ddy) > 0.2f) ? 1.0f : 0.0f;
    scale[row] = kept / (1e-8f + cnt / (float)NMC);
}

// ---------------- K2: pure scaled stream ---------------------------------
__global__ __launch_bounds__(256) void stream_kernel(
    const float* __restrict__ sig,
    const float* __restrict__ scale_arr,
    float* __restrict__ out,
    int T)
{
    const int row = blockIdx.x;
    const float scale = scale_arr[row];    // uniform address -> s_load
    const int t = threadIdx.x;

    const size_t base = (size_t)row * (size_t)T;
    const int n4 = T >> 2;                 // 750 for T=3000
    const v4f* __restrict__ in4  = (const v4f*)(sig + base);
    v4f* __restrict__       out4 = (v4f*)(out + base);

    // n4 = 750 = 2*256 + 238 -> 3-deep staging covers T=3000 exactly
    v4f v[3];
    #pragma unroll
    for (int u = 0; u < 3; ++u) {
        const int i = t + u * 256;
        if (i < n4) v[u] = __builtin_nontemporal_load(in4 + i);
    }
    #pragma unroll
    for (int u = 0; u < 3; ++u) {
        const int i = t + u * 256;
        if (i < n4) {
            v4f r = v[u];
            r *= scale;
            __builtin_nontemporal_store(r, out4 + i);
        }
    }
    // generic remainder for n4 > 768 (not hit at T=3000)
    for (int i = t + 768; i < n4; i += 256) {
        v4f r = __builtin_nontemporal_load(in4 + i);
        r *= scale;
        __builtin_nontemporal_store(r, out4 + i);
    }
    // scalar tail for T % 4 != 0 (not hit at T=3000)
    for (int i = (n4 << 2) + t; i < T; i += 256) {
        out[base + i] = sig[base + i] * scale;
    }
}

// ---------------- fallback: fused single kernel (round-1 version) --------
__global__ __launch_bounds__(256) void fused_kernel(
    const float* __restrict__ sig,
    const float* __restrict__ pos,
    const float* __restrict__ center,
    const float* __restrict__ mc,
    float* __restrict__ out,
    int T, int NMC)
{
    const int row  = blockIdx.x;
    const int t    = threadIdx.x;
    const int lane = t & 63;

    const size_t base = (size_t)row * (size_t)T;
    const int n4 = T >> 2;
    const v4f* __restrict__ in4  = (const v4f*)(sig + base);
    v4f* __restrict__       out4 = (v4f*)(out + base);

    v4f v[4];
    #pragma unroll
    for (int u = 0; u < 4; ++u) {
        const int i = t + u * 256;
        if (i < n4) v[u] = __builtin_nontemporal_load(in4 + i);
    }

    const float px = pos[2 * row + 0];
    const float py = pos[2 * row + 1];
    float cnt = 0.0f;
    for (int i = lane; i < NMC; i += 64) {
        const float dx = px - mc[2 * i + 0];
        const float dy = py - mc[2 * i + 1];
        cnt += (sqrtf(dx * dx + dy * dy) > 0.2f) ? 1.0f : 0.0f;
    }
    #pragma unroll
    for (int off = 32; off > 0; off >>= 1)
        cnt += __shfl_xor(cnt, off, 64);

    const float ddx  = px - center[0];
    const float ddy  = py - center[1];
    const float kept = (sqrtf(ddx * ddx + ddy * ddy) > 0.2f) ? 1.0f : 0.0f;
    const float scale = kept / (1e-8f + cnt / (float)NMC);

    #pragma unroll
    for (int u = 0; u < 4; ++u) {
        const int i = t + u * 256;
        if (i < n4) {
            v4f r = v[u];
            r *= scale;
            __builtin_nontemporal_store(r, out4 + i);
        }
    }
    for (int i = t + 1024; i < n4; i += 256) {
        v4f r = __builtin_nontemporal_load(in4 + i);
        r *= scale;
        __builtin_nontemporal_store(r, out4 + i);
    }
    for (int i = (n4 << 2) + t; i < T; i += 256) {
        out[base + i] = sig[base + i] * scale;
    }
}

extern "C" void kernel_launch(void* const* d_in, const int* in_sizes, int n_in,
                              void* d_out, int out_size, void* d_ws, size_t ws_size,
                              hipStream_t stream) {
    const float* sig    = (const float*)d_in[0];  // (B, C, T) f32
    const float* pos    = (const float*)d_in[1];  // (B, C, 2) f32
    const float* center = (const float*)d_in[2];  // (2,)      f32
    const float* mc     = (const float*)d_in[3];  // (N, 2)    f32
    float* out          = (float*)d_out;          // (B, C, T) f32

    const int rows = in_sizes[1] / 2;             // B*C = 17472
    const int T    = in_sizes[0] / rows;          // 3000
    const int NMC  = in_sizes[3] / 2;             // 100

    if (d_ws != nullptr && ws_size >= (size_t)rows * sizeof(float)
        && NMC <= 128) {
        float* scale = (float*)d_ws;
        const int sblocks = (rows + 255) / 256;
        scale_kernel<<<sblocks, 256, 0, stream>>>(
            pos, center, mc, scale, rows, NMC);
        stream_kernel<<<rows, 256, 0, stream>>>(sig, scale, out, T);
    } else {
        fused_kernel<<<rows, 256, 0, stream>>>(
            sig, pos, center, mc, out, T, NMC);
    }
}